// Round 15
// baseline (127.340 us; speedup 1.0000x reference)
//
#include <hip/hip_runtime.h>
#include <math.h>

#define VOCAB 32000
#define EMBED 200
#define HID   10
#define GATES 40
#define BSZ   256
#define SEQ   512
#define PF    8      // steps per prefetch block

#define RPB    64    // vocab rows per proj block
#define EPITCH 202   // eT row pitch (floats): 2-way bank alias = free
#define WROW   48    // wT row pitch (4 gate-groups x 12, b128-aligned)

__device__ __forceinline__ float rcp_fast(float x) { return __builtin_amdgcn_rcpf(x); }
__device__ __forceinline__ float exp2_fast(float x) { return __builtin_amdgcn_exp2f(x); }
__device__ __forceinline__ float readlane_f(float v, int l) {
    return __int_as_float(__builtin_amdgcn_readlane(__float_as_int(v), l));
}
// DPP quad_perm broadcast of quad-lane Q (pure VALU cross-lane, no LDS)
template <int Q>
__device__ __forceinline__ float quad_bcast(float v) {
    return __int_as_float(__builtin_amdgcn_mov_dpp(
        __float_as_int(v), Q * 0x55, 0xF, 0xF, true));
}

#define SC_SIG (-1.442695041f)   // -log2(e): sigmoid lanes
#define SC_TNH (-2.885390082f)   // -2*log2(e): tanh (g) lanes

// ---------------------------------------------------------------------------
// Kernel A: proj[v][g] = (embed[v,:] . Wih[g,:] + bias[g]) * amn[g]
// (UNCHANGED from R12, which passed with absmax 0.0.)
// ---------------------------------------------------------------------------
__global__ __launch_bounds__(256, 1) void proj_kernel(
    const float* __restrict__ embed, const float* __restrict__ Wih,
    const float* __restrict__ bih,   const float* __restrict__ bhh,
    float* __restrict__ proj)
{
    __shared__ float eT[RPB * EPITCH];     // 51.7 KB
    __shared__ float wT[EMBED * WROW];     // 38.4 KB

    const int tid = threadIdx.x;
    const int v0  = blockIdx.x * RPB;

    for (int idx = tid; idx < GATES * EMBED; idx += 256) {
        int g = idx / EMBED, k = idx - g * EMBED;
        wT[k * WROW + (g / 10) * 12 + (g % 10)] = Wih[idx];
    }
    {
        const float4* src = (const float4*)(embed + (size_t)v0 * EMBED);
        for (int f = tid; f < RPB * 50; f += 256) {
            float4 x = src[f];
            int r = f / 50, c = f - r * 50;
            float* dst = &eT[r * EPITCH + c * 4];
            dst[0] = x.x; dst[1] = x.y; dst[2] = x.z; dst[3] = x.w;
        }
    }
    __syncthreads();

    const int tr = tid & 63;
    const int tg = tid >> 6;

    float acc[10];
    #pragma unroll
    for (int i = 0; i < 10; ++i) acc[i] = 0.f;

    for (int k0 = 0; k0 < EMBED; k0 += 8) {
        float2 e01 = *(const float2*)&eT[tr * EPITCH + k0];
        float2 e23 = *(const float2*)&eT[tr * EPITCH + k0 + 2];
        float2 e45 = *(const float2*)&eT[tr * EPITCH + k0 + 4];
        float2 e67 = *(const float2*)&eT[tr * EPITCH + k0 + 6];
        float e[8] = {e01.x, e01.y, e23.x, e23.y, e45.x, e45.y, e67.x, e67.y};
        #pragma unroll
        for (int kk = 0; kk < 8; ++kk) {
            const float* wr = &wT[(k0 + kk) * WROW + tg * 12];
            float4 wa = *(const float4*)(wr);
            float4 wb = *(const float4*)(wr + 4);
            float2 wc = *(const float2*)(wr + 8);
            acc[0] = fmaf(e[kk], wa.x, acc[0]);
            acc[1] = fmaf(e[kk], wa.y, acc[1]);
            acc[2] = fmaf(e[kk], wa.z, acc[2]);
            acc[3] = fmaf(e[kk], wa.w, acc[3]);
            acc[4] = fmaf(e[kk], wb.x, acc[4]);
            acc[5] = fmaf(e[kk], wb.y, acc[5]);
            acc[6] = fmaf(e[kk], wb.z, acc[6]);
            acc[7] = fmaf(e[kk], wb.w, acc[7]);
            acc[8] = fmaf(e[kk], wc.x, acc[8]);
            acc[9] = fmaf(e[kk], wc.y, acc[9]);
        }
    }

    const float sc = (tg == 2) ? SC_TNH : SC_SIG;
    const int gbase = tg * 10;
    float* op = &proj[(size_t)(v0 + tr) * GATES + gbase];
    #pragma unroll
    for (int i = 0; i < 5; ++i) {
        float2 o;
        o.x = (acc[2*i]   + bih[gbase + 2*i]   + bhh[gbase + 2*i])   * sc;
        o.y = (acc[2*i+1] + bih[gbase + 2*i+1] + bhh[gbase + 2*i+1]) * sc;
        *(float2*)(op + 2 * i) = o;
    }
}

// ---------------------------------------------------------------------------
// Kernel B: recurrence, quad layout, TWO batch elements per wave (grid 128).
// The serial chain stalls ~180 cyc/step (load/trans/hazard latency) that one
// wave can't fill (R8/R12: dur invariant to VALU trims, VGPR stuck at 24).
// Interleaving an independent second recurrence in the same instruction
// stream fills those stalls regardless of their source. Shared w[] between
// batches; per-batch hs/c/gx. Tokens read straight from LDS at gather time
// (no tk rings) to keep VGPR < 64.
// ---------------------------------------------------------------------------
__global__ __launch_bounds__(64, 1) void lstm_rec(
    const int*   __restrict__ tok,  const float* __restrict__ proj,
    const float* __restrict__ h0,   const float* __restrict__ c0,
    const float* __restrict__ Whh,
    const float* __restrict__ W1,   const float* __restrict__ b1,
    const float* __restrict__ lng,  const float* __restrict__ lnb,
    const float* __restrict__ W2,   const float* __restrict__ b2,
    float* __restrict__ out)
{
    __shared__ int tok_s[2][SEQ + PF];

    const int bb   = blockIdx.x;               // 0..127
    const int bA   = 2 * bb, bB = 2 * bb + 1;  // batch indices
    const int lane = threadIdx.x;
    const int j0   = min(lane >> 2, HID - 1);  // hidden unit
    const int k4   = lane & 3;                 // gate class i/f/g/o
    const int gate = k4 * HID + j0;            // row in [i|f|g|o]-major order

    #pragma unroll
    for (int k = 0; k < SEQ / 64; ++k) {
        tok_s[0][k * 64 + lane] = tok[bA * SEQ + k * 64 + lane];
        tok_s[1][k * 64 + lane] = tok[bB * SEQ + k * 64 + lane];
    }
    if (lane < PF) { tok_s[0][SEQ + lane] = 0; tok_s[1][SEQ + lane] = 0; }
    __syncthreads();

    // activation constants: gate class 2 (g) computes tanh via 2*sig(2x)-1
    const float am  = (k4 == 2) ? 2.f : 1.f;
    const float amc = 1.f - am;
    const float amn = (k4 == 2) ? SC_TNH : SC_SIG;

    // W_hh row, pre-scaled so dot output feeds exp2 directly (shared A/B)
    float w[HID];
    #pragma unroll
    for (int j = 0; j < HID; ++j) w[j] = amn * Whh[gate * HID + j];

    // per-batch state
    float hsA[HID], hsB[HID];
    #pragma unroll
    for (int u = 0; u < HID; ++u) { hsA[u] = h0[bA * HID + u]; hsB[u] = h0[bB * HID + u]; }
    float cA = c0[bA * HID + j0];
    float cB = c0[bB * HID + j0];

    // ---- prologue: block-0 gathers in flight ----
    float gxA[PF], gxB[PF], gxAn[PF], gxBn[PF];
    #pragma unroll
    for (int k = 0; k < PF; ++k) {
        gxA[k] = proj[tok_s[0][k] * GATES + gate];
        gxB[k] = proj[tok_s[1][k] * GATES + gate];
    }

    for (int s0 = 0; s0 < SEQ; s0 += PF) {
        // issue next block's gathers (consumed PF steps from now; pad covers tail)
        #pragma unroll
        for (int k = 0; k < PF; ++k) {
            gxAn[k] = proj[tok_s[0][s0 + PF + k] * GATES + gate];
            gxBn[k] = proj[tok_s[1][s0 + PF + k] * GATES + gate];
        }

        // 8 fused step-pairs: two independent chains interleaved
        #pragma unroll
        for (int k = 0; k < PF; ++k) {
            float a0 = gxA[k], a1 = 0.f, a2 = 0.f, a3 = 0.f;
            float q0 = gxB[k], q1 = 0.f, q2 = 0.f, q3 = 0.f;
            a0 = fmaf(hsA[0], w[0], a0); q0 = fmaf(hsB[0], w[0], q0);
            a1 = fmaf(hsA[1], w[1], a1); q1 = fmaf(hsB[1], w[1], q1);
            a2 = fmaf(hsA[2], w[2], a2); q2 = fmaf(hsB[2], w[2], q2);
            a3 = fmaf(hsA[3], w[3], a3); q3 = fmaf(hsB[3], w[3], q3);
            a0 = fmaf(hsA[4], w[4], a0); q0 = fmaf(hsB[4], w[4], q0);
            a1 = fmaf(hsA[5], w[5], a1); q1 = fmaf(hsB[5], w[5], q1);
            a2 = fmaf(hsA[6], w[6], a2); q2 = fmaf(hsB[6], w[6], q2);
            a3 = fmaf(hsA[7], w[7], a3); q3 = fmaf(hsB[7], w[7], q3);
            a0 = fmaf(hsA[8], w[8], a0); q0 = fmaf(hsB[8], w[8], q0);
            a1 = fmaf(hsA[9], w[9], a1); q1 = fmaf(hsB[9], w[9], q1);
            float dtA = (a0 + a2) + (a1 + a3);
            float dtB = (q0 + q2) + (q1 + q3);

            float tA  = exp2_fast(dtA);      float tB  = exp2_fast(dtB);
            float sgA = rcp_fast(1.f + tA);  float sgB = rcp_fast(1.f + tB);
            float vA  = fmaf(am, sgA, amc);  float vB  = fmaf(am, sgB, amc);

            float ivA = quad_bcast<0>(vA);   float ivB = quad_bcast<0>(vB);
            float fvA = quad_bcast<1>(vA);   float fvB = quad_bcast<1>(vB);
            float gvA = quad_bcast<2>(vA);   float gvB = quad_bcast<2>(vB);
            float ovA = quad_bcast<3>(vA);   float ovB = quad_bcast<3>(vB);

            cA = fmaf(fvA, cA, ivA * gvA);   cB = fmaf(fvB, cB, ivB * gvB);
            float t2A = exp2_fast(cA * SC_TNH);
            float t2B = exp2_fast(cB * SC_TNH);
            float thA = fmaf(2.f, rcp_fast(1.f + t2A), -1.f);
            float thB = fmaf(2.f, rcp_fast(1.f + t2B), -1.f);
            float hA  = ovA * thA;           float hB  = ovB * thB;

            hsA[0] = readlane_f(hA, 0);  hsB[0] = readlane_f(hB, 0);
            hsA[1] = readlane_f(hA, 4);  hsB[1] = readlane_f(hB, 4);
            hsA[2] = readlane_f(hA, 8);  hsB[2] = readlane_f(hB, 8);
            hsA[3] = readlane_f(hA, 12); hsB[3] = readlane_f(hB, 12);
            hsA[4] = readlane_f(hA, 16); hsB[4] = readlane_f(hB, 16);
            hsA[5] = readlane_f(hA, 20); hsB[5] = readlane_f(hB, 20);
            hsA[6] = readlane_f(hA, 24); hsB[6] = readlane_f(hB, 24);
            hsA[7] = readlane_f(hA, 28); hsB[7] = readlane_f(hB, 28);
            hsA[8] = readlane_f(hA, 32); hsB[8] = readlane_f(hB, 32);
            hsA[9] = readlane_f(hA, 36); hsB[9] = readlane_f(hB, 36);
        }

        #pragma unroll
        for (int k = 0; k < PF; ++k) { gxA[k] = gxAn[k]; gxB[k] = gxBn[k]; }
    }

    // head for both batches (hs* are wave-uniform)
    if (lane == 0) {
        #pragma unroll
        for (int which = 0; which < 2; ++which) {
            const float* hv = which ? hsB : hsA;
            float z[5];
            float mu = 0.f;
            #pragma unroll
            for (int m = 0; m < 5; ++m) {
                float a = b1[m];
                #pragma unroll
                for (int j = 0; j < HID; ++j) a = fmaf(hv[j], W1[m * HID + j], a);
                z[m] = a; mu += a;
            }
            mu *= 0.2f;
            float var = 0.f;
            #pragma unroll
            for (int m = 0; m < 5; ++m) { float d = z[m] - mu; var = fmaf(d, d, var); }
            var *= 0.2f;
            float rs = rsqrtf(var + 1e-5f);
            float acc = b2[0];
            #pragma unroll
            for (int m = 0; m < 5; ++m) {
                float zn = fmaf((z[m] - mu) * rs, lng[m], lnb[m]);
                acc = fmaf(zn, W2[m], acc);
            }
            out[which ? bB : bA] = 1.f / (1.f + __expf(-acc));
        }
    }
}

extern "C" void kernel_launch(void* const* d_in, const int* in_sizes, int n_in,
                              void* d_out, int out_size, void* d_ws, size_t ws_size,
                              hipStream_t stream) {
    const int*   tok   = (const int*)  d_in[0];
    const float* h0    = (const float*)d_in[1];
    const float* c0    = (const float*)d_in[2];
    const float* embed = (const float*)d_in[3];
    const float* Wih   = (const float*)d_in[4];
    const float* Whh   = (const float*)d_in[5];
    const float* bih   = (const float*)d_in[6];
    const float* bhh   = (const float*)d_in[7];
    const float* W1    = (const float*)d_in[8];
    const float* b1    = (const float*)d_in[9];
    const float* lng   = (const float*)d_in[10];
    const float* lnb   = (const float*)d_in[11];
    const float* W2    = (const float*)d_in[12];
    const float* b2    = (const float*)d_in[13];
    float* out  = (float*)d_out;
    float* proj = (float*)d_ws;   // VOCAB*GATES*4 = 5.12 MB

    hipLaunchKernelGGL(proj_kernel, dim3(VOCAB / RPB), dim3(256), 0, stream,
                       embed, Wih, bih, bhh, proj);
    hipLaunchKernelGGL(lstm_rec, dim3(BSZ / 2), dim3(64), 0, stream,
                       tok, proj, h0, c0, Whh, W1, b1, lng, lnb, W2, b2, out);
}

// Round 16
// 108.079 us; speedup vs baseline: 1.1782x; 1.1782x over previous
//
#include <hip/hip_runtime.h>
#include <math.h>

#define VOCAB 32000
#define EMBED 200
#define HID   10
#define GATES 40
#define BSZ   256
#define SEQ   512
#define PF    8      // steps per prefetch block

#define RPB    64    // vocab rows per proj block
#define EPITCH 202   // eT row pitch (floats): 2-way bank alias = free
#define WROW   48    // wT row pitch (4 gate-groups x 12, b128-aligned)

__device__ __forceinline__ float rcp_fast(float x) { return __builtin_amdgcn_rcpf(x); }
__device__ __forceinline__ float exp2_fast(float x) { return __builtin_amdgcn_exp2f(x); }
__device__ __forceinline__ float readlane_f(float v, int l) {
    return __int_as_float(__builtin_amdgcn_readlane(__float_as_int(v), l));
}
// DPP quad_perm broadcast of quad-lane Q (pure VALU cross-lane, no LDS)
template <int Q>
__device__ __forceinline__ float quad_bcast(float v) {
    return __int_as_float(__builtin_amdgcn_mov_dpp(
        __float_as_int(v), Q * 0x55, 0xF, 0xF, true));
}

#define SC_SIG (-1.442695041f)   // -log2(e): sigmoid lanes
#define SC_TNH (-2.885390082f)   // -2*log2(e): tanh (g) lanes

// Inline-asm gather: the compiler refuses to keep a prefetch ring live
// (VGPR=24 across R8/R12/R15 -> loads sunk to just-before-use, ~200cyc L2
// latency on the serial chain every step). asm volatile loads cannot be
// sunk and their outputs must stay allocated.
#define GLOAD(dst, p) \
    asm volatile("global_load_dword %0, %1, off" : "=v"(dst) : "v"(p))
#define VMWAIT() do { \
    asm volatile("s_waitcnt vmcnt(0)" ::: "memory"); \
    __builtin_amdgcn_sched_barrier(0); \
} while (0)

// ---------------------------------------------------------------------------
// Kernel A: proj[v][g] = (embed[v,:] . Wih[g,:] + bias[g]) * amn[g]
// (UNCHANGED from R12, which passed with absmax 0.0.)
// ---------------------------------------------------------------------------
__global__ __launch_bounds__(256, 1) void proj_kernel(
    const float* __restrict__ embed, const float* __restrict__ Wih,
    const float* __restrict__ bih,   const float* __restrict__ bhh,
    float* __restrict__ proj)
{
    __shared__ float eT[RPB * EPITCH];     // 51.7 KB
    __shared__ float wT[EMBED * WROW];     // 38.4 KB

    const int tid = threadIdx.x;
    const int v0  = blockIdx.x * RPB;

    for (int idx = tid; idx < GATES * EMBED; idx += 256) {
        int g = idx / EMBED, k = idx - g * EMBED;
        wT[k * WROW + (g / 10) * 12 + (g % 10)] = Wih[idx];
    }
    {
        const float4* src = (const float4*)(embed + (size_t)v0 * EMBED);
        for (int f = tid; f < RPB * 50; f += 256) {
            float4 x = src[f];
            int r = f / 50, c = f - r * 50;
            float* dst = &eT[r * EPITCH + c * 4];
            dst[0] = x.x; dst[1] = x.y; dst[2] = x.z; dst[3] = x.w;
        }
    }
    __syncthreads();

    const int tr = tid & 63;
    const int tg = tid >> 6;

    float acc[10];
    #pragma unroll
    for (int i = 0; i < 10; ++i) acc[i] = 0.f;

    for (int k0 = 0; k0 < EMBED; k0 += 8) {
        float2 e01 = *(const float2*)&eT[tr * EPITCH + k0];
        float2 e23 = *(const float2*)&eT[tr * EPITCH + k0 + 2];
        float2 e45 = *(const float2*)&eT[tr * EPITCH + k0 + 4];
        float2 e67 = *(const float2*)&eT[tr * EPITCH + k0 + 6];
        float e[8] = {e01.x, e01.y, e23.x, e23.y, e45.x, e45.y, e67.x, e67.y};
        #pragma unroll
        for (int kk = 0; kk < 8; ++kk) {
            const float* wr = &wT[(k0 + kk) * WROW + tg * 12];
            float4 wa = *(const float4*)(wr);
            float4 wb = *(const float4*)(wr + 4);
            float2 wc = *(const float2*)(wr + 8);
            acc[0] = fmaf(e[kk], wa.x, acc[0]);
            acc[1] = fmaf(e[kk], wa.y, acc[1]);
            acc[2] = fmaf(e[kk], wa.z, acc[2]);
            acc[3] = fmaf(e[kk], wa.w, acc[3]);
            acc[4] = fmaf(e[kk], wb.x, acc[4]);
            acc[5] = fmaf(e[kk], wb.y, acc[5]);
            acc[6] = fmaf(e[kk], wb.z, acc[6]);
            acc[7] = fmaf(e[kk], wb.w, acc[7]);
            acc[8] = fmaf(e[kk], wc.x, acc[8]);
            acc[9] = fmaf(e[kk], wc.y, acc[9]);
        }
    }

    const float sc = (tg == 2) ? SC_TNH : SC_SIG;
    const int gbase = tg * 10;
    float* op = &proj[(size_t)(v0 + tr) * GATES + gbase];
    #pragma unroll
    for (int i = 0; i < 5; ++i) {
        float2 o;
        o.x = (acc[2*i]   + bih[gbase + 2*i]   + bhh[gbase + 2*i])   * sc;
        o.y = (acc[2*i+1] + bih[gbase + 2*i+1] + bhh[gbase + 2*i+1]) * sc;
        *(float2*)(op + 2 * i) = o;
    }
}

// ---------------------------------------------------------------------------
// Kernel B: recurrence, quad layout, 1 batch/wave (R12 structure — 2/wave
// regressed in R15 since wall = per-block chain). Gathers forced into a real
// register ring via inline asm; vmcnt(0) only at 8-step block boundaries.
// ---------------------------------------------------------------------------
__global__ __launch_bounds__(64, 1) void lstm_rec(
    const int*   __restrict__ tok,  const float* __restrict__ proj,
    const float* __restrict__ h0,   const float* __restrict__ c0,
    const float* __restrict__ Whh,
    const float* __restrict__ W1,   const float* __restrict__ b1,
    const float* __restrict__ lng,  const float* __restrict__ lnb,
    const float* __restrict__ W2,   const float* __restrict__ b2,
    float* __restrict__ out)
{
    __shared__ int tok_s[SEQ + PF];

    const int b    = blockIdx.x;
    const int lane = threadIdx.x;
    const int j0   = min(lane >> 2, HID - 1);  // hidden unit
    const int k4   = lane & 3;                 // gate class i/f/g/o
    const int gate = k4 * HID + j0;            // row in [i|f|g|o]-major order

    #pragma unroll
    for (int k = 0; k < SEQ / 64; ++k)
        tok_s[k * 64 + lane] = tok[b * SEQ + k * 64 + lane];
    if (lane < PF) tok_s[SEQ + lane] = 0;      // tail pad: safe addresses
    __syncthreads();

    const float am  = (k4 == 2) ? 2.f : 1.f;
    const float amc = 1.f - am;
    const float amn = (k4 == 2) ? SC_TNH : SC_SIG;

    // W_hh row, pre-scaled so dot output feeds exp2 directly
    float w[HID];
    #pragma unroll
    for (int j = 0; j < HID; ++j) w[j] = amn * Whh[gate * HID + j];

    float hs0 = h0[b * HID + 0], hs1 = h0[b * HID + 1], hs2 = h0[b * HID + 2];
    float hs3 = h0[b * HID + 3], hs4 = h0[b * HID + 4], hs5 = h0[b * HID + 5];
    float hs6 = h0[b * HID + 6], hs7 = h0[b * HID + 7], hs8 = h0[b * HID + 8];
    float hs9 = h0[b * HID + 9];
    float c_own = c0[b * HID + j0];

#define STEP(GX) do {                                                        \
    float a0 = (GX), a1 = 0.f, a2 = 0.f, a3 = 0.f;                           \
    a0 = fmaf(hs0, w[0], a0); a1 = fmaf(hs1, w[1], a1);                      \
    a2 = fmaf(hs2, w[2], a2); a3 = fmaf(hs3, w[3], a3);                      \
    a0 = fmaf(hs4, w[4], a0); a1 = fmaf(hs5, w[5], a1);                      \
    a2 = fmaf(hs6, w[6], a2); a3 = fmaf(hs7, w[7], a3);                      \
    a0 = fmaf(hs8, w[8], a0); a1 = fmaf(hs9, w[9], a1);                      \
    float dt  = (a0 + a2) + (a1 + a3);                                       \
    float t   = exp2_fast(dt);                                               \
    float sg  = rcp_fast(1.f + t);                                           \
    float val = fmaf(am, sg, amc);                                           \
    float iv = quad_bcast<0>(val);                                           \
    float fv = quad_bcast<1>(val);                                           \
    float gv = quad_bcast<2>(val);                                           \
    float ov = quad_bcast<3>(val);                                           \
    c_own = fmaf(fv, c_own, iv * gv);                                        \
    float t2 = exp2_fast(c_own * SC_TNH);                                    \
    float th = fmaf(2.f, rcp_fast(1.f + t2), -1.f);                          \
    float h_own = ov * th;                                                   \
    hs0 = readlane_f(h_own, 0);  hs1 = readlane_f(h_own, 4);                 \
    hs2 = readlane_f(h_own, 8);  hs3 = readlane_f(h_own, 12);                \
    hs4 = readlane_f(h_own, 16); hs5 = readlane_f(h_own, 20);                \
    hs6 = readlane_f(h_own, 24); hs7 = readlane_f(h_own, 28);                \
    hs8 = readlane_f(h_own, 32); hs9 = readlane_f(h_own, 36);                \
} while (0)

    // ---- prologue: block-0 gathers, pinned in regs via asm ----
    float gc0, gc1, gc2, gc3, gc4, gc5, gc6, gc7;
    float gn0, gn1, gn2, gn3, gn4, gn5, gn6, gn7;
    GLOAD(gc0, proj + tok_s[0] * GATES + gate);
    GLOAD(gc1, proj + tok_s[1] * GATES + gate);
    GLOAD(gc2, proj + tok_s[2] * GATES + gate);
    GLOAD(gc3, proj + tok_s[3] * GATES + gate);
    GLOAD(gc4, proj + tok_s[4] * GATES + gate);
    GLOAD(gc5, proj + tok_s[5] * GATES + gate);
    GLOAD(gc6, proj + tok_s[6] * GATES + gate);
    GLOAD(gc7, proj + tok_s[7] * GATES + gate);
    VMWAIT();

    for (int s0 = 0; s0 < SEQ; s0 += PF) {
        // issue next block's gathers (pad covers the tail block)
        GLOAD(gn0, proj + tok_s[s0 + 8]  * GATES + gate);
        GLOAD(gn1, proj + tok_s[s0 + 9]  * GATES + gate);
        GLOAD(gn2, proj + tok_s[s0 + 10] * GATES + gate);
        GLOAD(gn3, proj + tok_s[s0 + 11] * GATES + gate);
        GLOAD(gn4, proj + tok_s[s0 + 12] * GATES + gate);
        GLOAD(gn5, proj + tok_s[s0 + 13] * GATES + gate);
        GLOAD(gn6, proj + tok_s[s0 + 14] * GATES + gate);
        GLOAD(gn7, proj + tok_s[s0 + 15] * GATES + gate);

        STEP(gc0); STEP(gc1); STEP(gc2); STEP(gc3);
        STEP(gc4); STEP(gc5); STEP(gc6); STEP(gc7);

        VMWAIT();   // next block's loads complete (cover: 8 steps >> L2/HBM)
        gc0 = gn0; gc1 = gn1; gc2 = gn2; gc3 = gn3;
        gc4 = gn4; gc5 = gn5; gc6 = gn6; gc7 = gn7;
    }
#undef STEP

    // head: z = hn@W1^T + b1 ; LayerNorm(5) ; sigmoid(z@W2^T + b2)
    if (lane == 0) {
        float hv[HID] = {hs0, hs1, hs2, hs3, hs4, hs5, hs6, hs7, hs8, hs9};
        float z[5];
        float mu = 0.f;
        #pragma unroll
        for (int m = 0; m < 5; ++m) {
            float a = b1[m];
            #pragma unroll
            for (int j = 0; j < HID; ++j) a = fmaf(hv[j], W1[m * HID + j], a);
            z[m] = a; mu += a;
        }
        mu *= 0.2f;
        float var = 0.f;
        #pragma unroll
        for (int m = 0; m < 5; ++m) { float d = z[m] - mu; var = fmaf(d, d, var); }
        var *= 0.2f;
        float rs = rsqrtf(var + 1e-5f);
        float acc = b2[0];
        #pragma unroll
        for (int m = 0; m < 5; ++m) {
            float zn = fmaf((z[m] - mu) * rs, lng[m], lnb[m]);
            acc = fmaf(zn, W2[m], acc);
        }
        out[b] = 1.f / (1.f + __expf(-acc));
    }
}

extern "C" void kernel_launch(void* const* d_in, const int* in_sizes, int n_in,
                              void* d_out, int out_size, void* d_ws, size_t ws_size,
                              hipStream_t stream) {
    const int*   tok   = (const int*)  d_in[0];
    const float* h0    = (const float*)d_in[1];
    const float* c0    = (const float*)d_in[2];
    const float* embed = (const float*)d_in[3];
    const float* Wih   = (const float*)d_in[4];
    const float* Whh   = (const float*)d_in[5];
    const float* bih   = (const float*)d_in[6];
    const float* bhh   = (const float*)d_in[7];
    const float* W1    = (const float*)d_in[8];
    const float* b1    = (const float*)d_in[9];
    const float* lng   = (const float*)d_in[10];
    const float* lnb   = (const float*)d_in[11];
    const float* W2    = (const float*)d_in[12];
    const float* b2    = (const float*)d_in[13];
    float* out  = (float*)d_out;
    float* proj = (float*)d_ws;   // VOCAB*GATES*4 = 5.12 MB

    hipLaunchKernelGGL(proj_kernel, dim3(VOCAB / RPB), dim3(256), 0, stream,
                       embed, Wih, bih, bhh, proj);
    hipLaunchKernelGGL(lstm_rec, dim3(BSZ), dim3(64), 0, stream,
                       tok, proj, h0, c0, Whh, W1, b1, lng, lnb, W2, b2, out);
}

// Round 17
// 97.479 us; speedup vs baseline: 1.3063x; 1.1088x over previous
//
#include <hip/hip_runtime.h>
#include <math.h>

#define VOCAB 32000
#define EMBED 200
#define HID   10
#define GATES 40
#define BSZ   256
#define SEQ   512
#define PF    8      // steps per prefetch block

#define RPB    128   // vocab rows per proj block (250 blocks = 1 round on 256 CUs)
#define EPITCH 202   // eT row pitch (floats): 2-way bank alias = free
#define WROW   48    // wT row pitch (4 gate-groups x 12, b128-aligned)

__device__ __forceinline__ float rcp_fast(float x) { return __builtin_amdgcn_rcpf(x); }
__device__ __forceinline__ float exp2_fast(float x) { return __builtin_amdgcn_exp2f(x); }
__device__ __forceinline__ float readlane_f(float v, int l) {
    return __int_as_float(__builtin_amdgcn_readlane(__float_as_int(v), l));
}
// DPP quad_perm broadcast of quad-lane Q (pure VALU cross-lane, no LDS)
template <int Q>
__device__ __forceinline__ float quad_bcast(float v) {
    return __int_as_float(__builtin_amdgcn_mov_dpp(
        __float_as_int(v), Q * 0x55, 0xF, 0xF, true));
}

#define SC_SIG (-1.442695041f)   // -log2(e): sigmoid lanes
#define SC_TNH (-2.885390082f)   // -2*log2(e): tanh (g) lanes

// ---------------------------------------------------------------------------
// Kernel A: proj[v][g] = (embed[v,:] . Wih[g,:] + bias[g]) * amn[g]
// 250 blocks x 256 thr, 128 rows/block (one dispatch round on 256 CUs; the
// 500-block version needed two). Thread = 2 rows x 10 gates -> 20 FMA per
// LDS-k, amortizing the wave-uniform wT broadcast reads. LDS 142 KB (<160).
// ---------------------------------------------------------------------------
__global__ __launch_bounds__(256, 1) void proj_kernel(
    const float* __restrict__ embed, const float* __restrict__ Wih,
    const float* __restrict__ bih,   const float* __restrict__ bhh,
    float* __restrict__ proj)
{
    __shared__ float eT[RPB * EPITCH];     // 103.4 KB
    __shared__ float wT[EMBED * WROW];     // 38.4 KB

    const int tid = threadIdx.x;
    const int v0  = blockIdx.x * RPB;

    // stage W transposed+padded: wT[k][(g/10)*12 + g%10] = Wih[g*EMBED+k]
    for (int idx = tid; idx < GATES * EMBED; idx += 256) {
        int g = idx / EMBED, k = idx - g * EMBED;
        wT[k * WROW + (g / 10) * 12 + (g % 10)] = Wih[idx];
    }
    // stage 128 embed rows (contiguous float4 block, coalesced)
    {
        const float4* src = (const float4*)(embed + (size_t)v0 * EMBED);
        for (int f = tid; f < RPB * 50; f += 256) {
            float4 x = src[f];
            int r = f / 50, c = f - r * 50;
            float* dst = &eT[r * EPITCH + c * 4];
            dst[0] = x.x; dst[1] = x.y; dst[2] = x.z; dst[3] = x.w;
        }
    }
    __syncthreads();

    const int tr = tid & 63;       // first row; second row = tr + 64
    const int tg = tid >> 6;       // gate group (== gate class), wave-uniform

    float accA[10], accB[10];
    #pragma unroll
    for (int i = 0; i < 10; ++i) { accA[i] = 0.f; accB[i] = 0.f; }

    for (int k0 = 0; k0 < EMBED; k0 += 8) {
        const float* eA = &eT[tr * EPITCH + k0];
        const float* eB = &eT[(tr + 64) * EPITCH + k0];
        float2 a01 = *(const float2*)(eA);     float2 b01 = *(const float2*)(eB);
        float2 a23 = *(const float2*)(eA + 2); float2 b23 = *(const float2*)(eB + 2);
        float2 a45 = *(const float2*)(eA + 4); float2 b45 = *(const float2*)(eB + 4);
        float2 a67 = *(const float2*)(eA + 6); float2 b67 = *(const float2*)(eB + 6);
        float ea[8] = {a01.x, a01.y, a23.x, a23.y, a45.x, a45.y, a67.x, a67.y};
        float eb[8] = {b01.x, b01.y, b23.x, b23.y, b45.x, b45.y, b67.x, b67.y};
        #pragma unroll
        for (int kk = 0; kk < 8; ++kk) {
            const float* wr = &wT[(k0 + kk) * WROW + tg * 12];
            float4 wa = *(const float4*)(wr);
            float4 wb = *(const float4*)(wr + 4);
            float2 wc = *(const float2*)(wr + 8);
            accA[0] = fmaf(ea[kk], wa.x, accA[0]); accB[0] = fmaf(eb[kk], wa.x, accB[0]);
            accA[1] = fmaf(ea[kk], wa.y, accA[1]); accB[1] = fmaf(eb[kk], wa.y, accB[1]);
            accA[2] = fmaf(ea[kk], wa.z, accA[2]); accB[2] = fmaf(eb[kk], wa.z, accB[2]);
            accA[3] = fmaf(ea[kk], wa.w, accA[3]); accB[3] = fmaf(eb[kk], wa.w, accB[3]);
            accA[4] = fmaf(ea[kk], wb.x, accA[4]); accB[4] = fmaf(eb[kk], wb.x, accB[4]);
            accA[5] = fmaf(ea[kk], wb.y, accA[5]); accB[5] = fmaf(eb[kk], wb.y, accB[5]);
            accA[6] = fmaf(ea[kk], wb.z, accA[6]); accB[6] = fmaf(eb[kk], wb.z, accB[6]);
            accA[7] = fmaf(ea[kk], wb.w, accA[7]); accB[7] = fmaf(eb[kk], wb.w, accB[7]);
            accA[8] = fmaf(ea[kk], wc.x, accA[8]); accB[8] = fmaf(eb[kk], wc.x, accB[8]);
            accA[9] = fmaf(ea[kk], wc.y, accA[9]); accB[9] = fmaf(eb[kk], wc.y, accB[9]);
        }
    }

    // epilogue: bias + activation exp2-scale fold; float2 stores, 2 rows
    const float sc = (tg == 2) ? SC_TNH : SC_SIG;
    const int gbase = tg * 10;
    float bb[10];
    #pragma unroll
    for (int i = 0; i < 10; ++i) bb[i] = bih[gbase + i] + bhh[gbase + i];
    float* opA = &proj[(size_t)(v0 + tr) * GATES + gbase];
    float* opB = &proj[(size_t)(v0 + tr + 64) * GATES + gbase];
    #pragma unroll
    for (int i = 0; i < 5; ++i) {
        float2 oA, oB;
        oA.x = (accA[2*i]   + bb[2*i])   * sc;
        oA.y = (accA[2*i+1] + bb[2*i+1]) * sc;
        oB.x = (accB[2*i]   + bb[2*i])   * sc;
        oB.y = (accB[2*i+1] + bb[2*i+1]) * sc;
        *(float2*)(opA + 2 * i) = oA;
        *(float2*)(opB + 2 * i) = oB;
    }
}

// ---------------------------------------------------------------------------
// Kernel B: recurrence — EXACT revert to the R12-passing 69 us version.
// (R15 2-batch ILP: 97 us; R16 asm-pinned ring: 78 us; both falsified.
// 322 cyc/step = serial-chain issue+latency; wall = SEQ x chain.)
// ---------------------------------------------------------------------------
__global__ __launch_bounds__(64, 1) void lstm_rec(
    const int*   __restrict__ tok,  const float* __restrict__ proj,
    const float* __restrict__ h0,   const float* __restrict__ c0,
    const float* __restrict__ Whh,
    const float* __restrict__ W1,   const float* __restrict__ b1,
    const float* __restrict__ lng,  const float* __restrict__ lnb,
    const float* __restrict__ W2,   const float* __restrict__ b2,
    float* __restrict__ out)
{
    __shared__ int tok_s[SEQ + 2 * PF];

    const int b    = blockIdx.x;
    const int lane = threadIdx.x;
    const int j0   = min(lane >> 2, HID - 1);  // hidden unit
    const int k4   = lane & 3;                 // gate class i/f/g/o
    const int gate = k4 * HID + j0;            // row in [i|f|g|o]-major order

    #pragma unroll
    for (int k = 0; k < SEQ / 64; ++k)
        tok_s[k * 64 + lane] = tok[b * SEQ + k * 64 + lane];
    if (lane < 2 * PF) tok_s[SEQ + lane] = 0;  // tail pad: safe addresses
    __syncthreads();

    const float am  = (k4 == 2) ? 2.f : 1.f;
    const float amc = 1.f - am;
    const float amn = (k4 == 2) ? SC_TNH : SC_SIG;

    // W_hh row, pre-scaled so dot output feeds exp2 directly
    float w[HID];
    #pragma unroll
    for (int j = 0; j < HID; ++j) w[j] = amn * Whh[gate * HID + j];

    float hs[HID];
    #pragma unroll
    for (int u = 0; u < HID; ++u) hs[u] = h0[b * HID + u];
    float c_own = c0[b * HID + j0];

    // ---- prologue ----
    int   tk_cur[PF], tk_nxt[PF];
    float gx_cur[PF], gx_nxt[PF];
    #pragma unroll
    for (int k = 0; k < PF; ++k) tk_cur[k] = tok_s[k];
    #pragma unroll
    for (int k = 0; k < PF; ++k) gx_cur[k] = proj[tk_cur[k] * GATES + gate];
    #pragma unroll
    for (int k = 0; k < PF; ++k) tk_nxt[k] = tok_s[PF + k];

    for (int s0 = 0; s0 < SEQ; s0 += PF) {
        #pragma unroll
        for (int k = 0; k < PF; ++k)
            gx_nxt[k] = proj[tk_nxt[k] * GATES + gate];
        #pragma unroll
        for (int k = 0; k < PF; ++k)
            tk_cur[k] = tok_s[s0 + 2 * PF + k];

        #pragma unroll
        for (int k = 0; k < PF; ++k) {
            float a0 = gx_cur[k], a1 = 0.f, a2 = 0.f, a3 = 0.f;
            a0 = fmaf(hs[0], w[0], a0); a1 = fmaf(hs[1], w[1], a1);
            a2 = fmaf(hs[2], w[2], a2); a3 = fmaf(hs[3], w[3], a3);
            a0 = fmaf(hs[4], w[4], a0); a1 = fmaf(hs[5], w[5], a1);
            a2 = fmaf(hs[6], w[6], a2); a3 = fmaf(hs[7], w[7], a3);
            a0 = fmaf(hs[8], w[8], a0); a1 = fmaf(hs[9], w[9], a1);
            float dt = (a0 + a2) + (a1 + a3);

            float t   = exp2_fast(dt);
            float sg  = rcp_fast(1.f + t);
            float val = fmaf(am, sg, amc);

            float iv = quad_bcast<0>(val);
            float fv = quad_bcast<1>(val);
            float gv = quad_bcast<2>(val);
            float ov = quad_bcast<3>(val);

            c_own = fmaf(fv, c_own, iv * gv);
            float t2 = exp2_fast(c_own * SC_TNH);
            float th = fmaf(2.f, rcp_fast(1.f + t2), -1.f);
            float h_own = ov * th;

            hs[0] = readlane_f(h_own, 0);  hs[1] = readlane_f(h_own, 4);
            hs[2] = readlane_f(h_own, 8);  hs[3] = readlane_f(h_own, 12);
            hs[4] = readlane_f(h_own, 16); hs[5] = readlane_f(h_own, 20);
            hs[6] = readlane_f(h_own, 24); hs[7] = readlane_f(h_own, 28);
            hs[8] = readlane_f(h_own, 32); hs[9] = readlane_f(h_own, 36);
        }

        #pragma unroll
        for (int k = 0; k < PF; ++k) {
            gx_cur[k] = gx_nxt[k];
            tk_nxt[k] = tk_cur[k];
        }
    }

    // head: z = hn@W1^T + b1 ; LayerNorm(5) ; sigmoid(z@W2^T + b2)
    if (lane == 0) {
        float z[5];
        float mu = 0.f;
        #pragma unroll
        for (int m = 0; m < 5; ++m) {
            float a = b1[m];
            #pragma unroll
            for (int j = 0; j < HID; ++j) a = fmaf(hs[j], W1[m * HID + j], a);
            z[m] = a; mu += a;
        }
        mu *= 0.2f;
        float var = 0.f;
        #pragma unroll
        for (int m = 0; m < 5; ++m) { float d = z[m] - mu; var = fmaf(d, d, var); }
        var *= 0.2f;
        float rs = rsqrtf(var + 1e-5f);
        float acc = b2[0];
        #pragma unroll
        for (int m = 0; m < 5; ++m) {
            float zn = fmaf((z[m] - mu) * rs, lng[m], lnb[m]);
            acc = fmaf(zn, W2[m], acc);
        }
        out[b] = 1.f / (1.f + __expf(-acc));
    }
}

extern "C" void kernel_launch(void* const* d_in, const int* in_sizes, int n_in,
                              void* d_out, int out_size, void* d_ws, size_t ws_size,
                              hipStream_t stream) {
    const int*   tok   = (const int*)  d_in[0];
    const float* h0    = (const float*)d_in[1];
    const float* c0    = (const float*)d_in[2];
    const float* embed = (const float*)d_in[3];
    const float* Wih   = (const float*)d_in[4];
    const float* Whh   = (const float*)d_in[5];
    const float* bih   = (const float*)d_in[6];
    const float* bhh   = (const float*)d_in[7];
    const float* W1    = (const float*)d_in[8];
    const float* b1    = (const float*)d_in[9];
    const float* lng   = (const float*)d_in[10];
    const float* lnb   = (const float*)d_in[11];
    const float* W2    = (const float*)d_in[12];
    const float* b2    = (const float*)d_in[13];
    float* out  = (float*)d_out;
    float* proj = (float*)d_ws;   // VOCAB*GATES*4 = 5.12 MB

    hipLaunchKernelGGL(proj_kernel, dim3(VOCAB / RPB), dim3(256), 0, stream,
                       embed, Wih, bih, bhh, proj);
    hipLaunchKernelGGL(lstm_rec, dim3(BSZ), dim3(64), 0, stream,
                       tok, proj, h0, c0, Whh, W1, b1, lng, lnb, W2, b2, out);
}